// Round 1
// baseline (389.315 us; speedup 1.0000x reference)
//
#include <hip/hip_runtime.h>
#include <hip/hip_fp16.h>

// Affinity propagation, [X=256,Y=256,Z=32] fp32, 3 iterations x 3 dirs.
//
// R9: un-fuse. R8's LDS-fused iter3 ran at 2 blocks/CU (69 KB LDS x2 bufs,
// grid=512) with 4 barriers => ~2 waves/SIMD of MLP; the 96 MiB/iter weight
// stream (the only large operand, zero intra-iteration reuse) was read at
// ~2 TB/s effective plus 23% halo duplication. New structure:
//   make_w  : same proven math, but voxel-major store [dir][x][y][z] so each
//             thread writes 4 consecutive H8 records (64 B contiguous).
//   wstep   : 9 streaming kernels (prop_step's R1-proven neighbor logic) that
//             read 4 packed-fp16 weight records (64 B contiguous per thread,
//             4 KiB per wave) instead of guidance+renormalize. No LDS, 2048
//             blocks, full occupancy; r (8 MiB) rides in L2/L3; weights
//             (96 MiB) fit L3 so iterations 2-3 read at L3 speed.
// OOB semantics ride on weights==0 across edges (zeroed in make_w);
// clamped reads keep OOB neighbor values finite (always multiplied by 0).

constexpr int NV = 256 * 256 * 32;   // 2097152
constexpr int YZ = 256 * 32;         // 8192
constexpr int NG = NV / 4;
constexpr int GEND = 24 * NV;

struct alignas(16) H8 { __half2 h[4]; };   // 8 fp16 weights per voxel

__device__ __forceinline__ int iclamp(int v, int lo, int hi) {
    return min(max(v, lo), hi);
}

__device__ __forceinline__ void unpack8(const H8& r, float* w) {
    float2 f;
    f = __half22float2(r.h[0]); w[0] = f.x; w[1] = f.y;
    f = __half22float2(r.h[1]); w[2] = f.x; w[3] = f.y;
    f = __half22float2(r.h[2]); w[4] = f.x; w[5] = f.y;
    f = __half22float2(r.h[3]); w[6] = f.x; w[7] = f.y;
}

// ---------------- weight precompute (voxel-major store) ----------------
template <int DIR>
__device__ __forceinline__ void wgroup_t(int f0, const float* __restrict__ g,
                                         H8* __restrict__ wt) {
    constexpr int d1[8] = {1, 1, 1, 0, 0, -1, -1, -1};
    constexpr int d2[8] = {1, 0, -1, 1, -1, 1, 0, -1};
    const int z = f0 & 31, y = (f0 >> 5) & 255, x = f0 >> 13;
    const int gb0 = DIR * 8 * NV;

    float G[8][4];

    if (DIR == 0) {
#pragma unroll
        for (int k = 0; k < 8; ++k) {
            const int a = x + d1[k], b = y + d2[k];
            const bool valid = ((unsigned)a < 256u) & ((unsigned)b < 256u);
            const int ofs = f0 + d1[k] * YZ + d2[k] * 32;
            float4 gv = *(const float4*)(g + iclamp(gb0 + k * NV + ofs, 0, GEND - 4));
            if (!valid) { gv.x = 0.f; gv.y = 0.f; gv.z = 0.f; gv.w = 0.f; }
            G[k][0] = gv.x; G[k][1] = gv.y; G[k][2] = gv.z; G[k][3] = gv.w;
        }
    } else {
        const int s1 = (DIR == 1) ? YZ : 32;
        const int c1 = (DIR == 1) ? x : y;
        const bool zlo = (z > 0), zhi = (z < 28);
#pragma unroll
        for (int k = 0; k < 8; ++k) {
            const bool vrow = (unsigned)(c1 + d1[k]) < 256u;
            const int gb = gb0 + k * NV + f0 + d1[k] * s1;
            float4 gv = *(const float4*)(g + iclamp(gb, 0, GEND - 4));
            if (!vrow) { gv.x = 0.f; gv.y = 0.f; gv.z = 0.f; gv.w = 0.f; }
            if (d2[k] == 1) {
                float ge = g[iclamp(gb + 4, 0, GEND - 1)];
                ge = (vrow && zhi) ? ge : 0.f;
                G[k][0] = gv.y; G[k][1] = gv.z; G[k][2] = gv.w; G[k][3] = ge;
            } else if (d2[k] == -1) {
                float ge = g[iclamp(gb - 1, 0, GEND - 1)];
                ge = (vrow && zlo) ? ge : 0.f;
                G[k][0] = ge; G[k][1] = gv.x; G[k][2] = gv.y; G[k][3] = gv.z;
            } else {
                G[k][0] = gv.x; G[k][1] = gv.y; G[k][2] = gv.z; G[k][3] = gv.w;
            }
        }
    }

#pragma unroll
    for (int i = 0; i < 4; ++i) {
        float asum = 0.f;
#pragma unroll
        for (int k = 0; k < 8; ++k) asum += fabsf(G[k][i]);
        const float winv = __builtin_amdgcn_rcpf(asum);
        H8 rec;
#pragma unroll
        for (int p = 0; p < 4; ++p)
            rec.h[p] = __floats2half2_rn(G[2 * p][i] * winv, G[2 * p + 1][i] * winv);
        wt[DIR * NV + f0 + i] = rec;   // voxel-major: 4 consecutive records/thread
    }
}

__global__ __launch_bounds__(256) void make_w(const float* __restrict__ g,
                                              H8* __restrict__ wt) {
    const int b = blockIdx.x;
    const int dir = b >> 11;                 // 2048 blocks per dir
    const int f0 = ((b & 2047) * 256 + threadIdx.x) << 2;
    if (dir == 0)      wgroup_t<0>(f0, g, wt);
    else if (dir == 1) wgroup_t<1>(f0, g, wt);
    else               wgroup_t<2>(f0, g, wt);
}

// ---------------- streaming propagation step (precomputed weights) ----------------
template <int DIR>
__global__ __launch_bounds__(256) void wstep(const H8* __restrict__ wt,
                                             const float* __restrict__ rin,
                                             float* __restrict__ rout) {
    constexpr int d1[8] = {1, 1, 1, 0, 0, -1, -1, -1};
    constexpr int d2[8] = {1, 0, -1, 1, -1, 1, 0, -1};
    const int t = blockIdx.x * 256 + threadIdx.x;
    const int f0 = t << 2;

    // 4 weight records = 64 B contiguous per thread (4 KiB per wave)
    const H8* wp = wt + DIR * NV + f0;
    float w[4][8];
#pragma unroll
    for (int i = 0; i < 4; ++i) unpack8(wp[i], w[i]);

    float a[4];

    if (DIR == 0) {
        const float4 rc = *(const float4*)(rin + f0);
        const float rc4[4] = {rc.x, rc.y, rc.z, rc.w};
        a[0] = rc.x; a[1] = rc.y; a[2] = rc.z; a[3] = rc.w;
#pragma unroll
        for (int k = 0; k < 8; ++k) {
            const int ofs = f0 + d1[k] * YZ + d2[k] * 32;
            const float4 rv = *(const float4*)(rin + iclamp(ofs, 0, NV - 4));
            const float nb[4] = {rv.x, rv.y, rv.z, rv.w};
#pragma unroll
            for (int i = 0; i < 4; ++i)
                a[i] = fmaf(w[i][k], nb[i] - rc4[i], a[i]);
        }
    } else {
        constexpr int s1 = (DIR == 1) ? YZ : 32;
        float e[3][6];   // per x/y-row: [z-1, z0..z3, z+4]; constant-indexed only
#pragma unroll
        for (int j = 0; j < 3; ++j) {           // d1 = +1, 0, -1
            const int ro = f0 + (1 - j) * s1;
            const float4 rv = *(const float4*)(rin + iclamp(ro, 0, NV - 4));
            e[j][0] = rin[iclamp(ro - 1, 0, NV - 1)];
            e[j][1] = rv.x; e[j][2] = rv.y; e[j][3] = rv.z; e[j][4] = rv.w;
            e[j][5] = rin[iclamp(ro + 4, 0, NV - 1)];
        }
        const float rc4[4] = {e[1][1], e[1][2], e[1][3], e[1][4]};
        a[0] = rc4[0]; a[1] = rc4[1]; a[2] = rc4[2]; a[3] = rc4[3];
#pragma unroll
        for (int k = 0; k < 8; ++k) {
            const int j = 1 - d1[k];
#pragma unroll
            for (int i = 0; i < 4; ++i)
                a[i] = fmaf(w[i][k], e[j][1 + i + d2[k]] - rc4[i], a[i]);
        }
    }

    *(float4*)(rout + f0) = make_float4(a[0], a[1], a[2], a[3]);
}

// ---------------- fallback (R1-proven): direct-from-guidance steps ----------------
template <int DIR>
__global__ __launch_bounds__(256) void prop_step(const float* __restrict__ g,
                                                 const float* __restrict__ rin,
                                                 float* __restrict__ rout) {
    constexpr int d1[8] = {1, 1, 1, 0, 0, -1, -1, -1};
    constexpr int d2[8] = {1, 0, -1, 1, -1, 1, 0, -1};
    const int t = blockIdx.x * 256 + threadIdx.x;
    const int f0 = t << 2;
    const int z = f0 & 31, y = (f0 >> 5) & 255, x = f0 >> 13;
    const int gb0 = DIR * 8 * NV;

    float as[4] = {0, 0, 0, 0}, ac[4] = {0, 0, 0, 0};
    float4 rc;

    if (DIR == 0) {
        rc = *(const float4*)(rin + f0);
#pragma unroll
        for (int k = 0; k < 8; ++k) {
            const int a = x + d1[k], b = y + d2[k];
            const bool valid = ((unsigned)a < 256u) & ((unsigned)b < 256u);
            const int ofs = f0 + d1[k] * YZ + d2[k] * 32;
            const float4 rv = *(const float4*)(rin + iclamp(ofs, 0, NV - 4));
            float4 gv = *(const float4*)(g + iclamp(gb0 + k * NV + ofs, 0, GEND - 4));
            if (!valid) { gv.x = 0.f; gv.y = 0.f; gv.z = 0.f; gv.w = 0.f; }
            as[0] += fabsf(gv.x); as[1] += fabsf(gv.y);
            as[2] += fabsf(gv.z); as[3] += fabsf(gv.w);
            ac[0] = fmaf(gv.x, rv.x - rc.x, ac[0]); ac[1] = fmaf(gv.y, rv.y - rc.y, ac[1]);
            ac[2] = fmaf(gv.z, rv.z - rc.z, ac[2]); ac[3] = fmaf(gv.w, rv.w - rc.w, ac[3]);
        }
    } else {
        const int s1 = (DIR == 1) ? YZ : 32;
        const int c1 = (DIR == 1) ? x : y;
        float4 rv[3]; float rl[3], rr[3];
#pragma unroll
        for (int j = 0; j < 3; ++j) {
            const int ro = f0 + (1 - j) * s1;
            rv[j] = *(const float4*)(rin + iclamp(ro, 0, NV - 4));
            rl[j] = rin[iclamp(ro - 1, 0, NV - 1)];
            rr[j] = rin[iclamp(ro + 4, 0, NV - 1)];
        }
        rc = rv[1];
        const bool zlo = (z > 0), zhi = (z < 28);
#pragma unroll
        for (int k = 0; k < 8; ++k) {
            const int j = 1 - d1[k];
            const bool vrow = (unsigned)(c1 + d1[k]) < 256u;
            const int gb = gb0 + k * NV + f0 + d1[k] * s1;
            float4 gv = *(const float4*)(g + iclamp(gb, 0, GEND - 4));
            if (!vrow) { gv.x = 0.f; gv.y = 0.f; gv.z = 0.f; gv.w = 0.f; }
            float4 gk, rk;
            if (d2[k] == 1) {
                float ge = g[iclamp(gb + 4, 0, GEND - 1)];
                ge = (vrow && zhi) ? ge : 0.f;
                gk = make_float4(gv.y, gv.z, gv.w, ge);
                rk = make_float4(rv[j].y, rv[j].z, rv[j].w, rr[j]);
            } else if (d2[k] == -1) {
                float ge = g[iclamp(gb - 1, 0, GEND - 1)];
                ge = (vrow && zlo) ? ge : 0.f;
                gk = make_float4(ge, gv.x, gv.y, gv.z);
                rk = make_float4(rl[j], rv[j].x, rv[j].y, rv[j].z);
            } else {
                gk = gv; rk = rv[j];
            }
            as[0] += fabsf(gk.x); as[1] += fabsf(gk.y);
            as[2] += fabsf(gk.z); as[3] += fabsf(gk.w);
            ac[0] = fmaf(gk.x, rk.x - rc.x, ac[0]); ac[1] = fmaf(gk.y, rk.y - rc.y, ac[1]);
            ac[2] = fmaf(gk.z, rk.z - rc.z, ac[2]); ac[3] = fmaf(gk.w, rk.w - rc.w, ac[3]);
        }
    }

    float4 o;
    o.x = rc.x + ac[0] * __builtin_amdgcn_rcpf(as[0]);
    o.y = rc.y + ac[1] * __builtin_amdgcn_rcpf(as[1]);
    o.z = rc.z + ac[2] * __builtin_amdgcn_rcpf(as[2]);
    o.w = rc.w + ac[3] * __builtin_amdgcn_rcpf(as[3]);
    *(float4*)(rout + f0) = o;
}

extern "C" void kernel_launch(void* const* d_in, const int* in_sizes, int n_in,
                              void* d_out, int out_size, void* d_ws, size_t ws_size,
                              hipStream_t stream) {
    const float* g    = (const float*)d_in[0];
    const float* blur = (const float*)d_in[1];
    float* out = (float*)d_out;

    const size_t WBYTES = (size_t)3 * NV * sizeof(H8);            // 96 MiB
    const size_t NEED   = WBYTES + (size_t)2 * NV * sizeof(float);

    if (ws_size >= NEED) {
        H8*    wt   = (H8*)d_ws;
        float* bufA = (float*)((char*)d_ws + WBYTES);
        float* bufB = bufA + NV;

        make_w<<<dim3(3 * NG / 256), dim3(256), 0, stream>>>(g, wt);

        const float* src = blur;
        for (int step = 0; step < 9; ++step) {
            float* dst = (step == 8) ? out : ((step & 1) ? bufB : bufA);
            switch (step % 3) {
                case 0: wstep<0><<<dim3(NG / 256), dim3(256), 0, stream>>>(wt, src, dst); break;
                case 1: wstep<1><<<dim3(NG / 256), dim3(256), 0, stream>>>(wt, src, dst); break;
                case 2: wstep<2><<<dim3(NG / 256), dim3(256), 0, stream>>>(wt, src, dst); break;
            }
            src = dst;
        }
    } else {
        // fallback: R1-proven direct path (needs only 8 MiB of ws)
        float* ws = (float*)d_ws;
        const dim3 block(256), sgrid(NG / 256);
        const float* src = blur;
        for (int step = 0; step < 9; ++step) {
            float* dst = (step & 1) ? ws : out;
            switch (step % 3) {
                case 0: prop_step<0><<<sgrid, block, 0, stream>>>(g, src, dst); break;
                case 1: prop_step<1><<<sgrid, block, 0, stream>>>(g, src, dst); break;
                case 2: prop_step<2><<<sgrid, block, 0, stream>>>(g, src, dst); break;
            }
            src = dst;
        }
    }
}